// Round 1
// baseline (58.694 us; speedup 1.0000x reference)
//
#include <hip/hip_runtime.h>
#include <math.h>

#define HH 128   // hidden size
#define SS 1000  // sequence length
#define NT 1024  // threads per block (16 waves)
#define NW (NT / 64)

// ws layout (floats):
//   [0 .. 4H)    float4 k4[h] = {A0, A1, ad, v}
//   [4H .. 5H)   cc   (bias part of z)
//   [5H .. 6H)   w30  (W3 @ enc_s_w[:,0])
//   [6H .. 7H)   w31  (W3 @ enc_s_w[:,1])
//   [7H .. 8H)   w3b  (W3 @ enc_s_b)
__global__ void sc_precompute(const float* __restrict__ enc_s_w,
                              const float* __restrict__ enc_s_b,
                              const float* __restrict__ enc_d_w,
                              const float* __restrict__ enc_d_b,
                              const float* __restrict__ v,
                              const float* __restrict__ W,
                              float* __restrict__ ws) {
    int h = threadIdx.x;
    if (h >= HH) return;
    const float* Wr = W + h * (3 * HH);
    float a0 = 0.f, a1 = 0.f, ad = 0.f, cc = 0.f, w30 = 0.f, w31 = 0.f, w3b = 0.f;
    for (int k = 0; k < HH; ++k) {
        float w1 = Wr[k], w2 = Wr[HH + k], w3 = Wr[2 * HH + k];
        a0  = fmaf(w1, enc_s_w[2 * k + 0], a0);
        a1  = fmaf(w1, enc_s_w[2 * k + 1], a1);
        ad  = fmaf(w2, enc_d_w[2 * k + 0] + enc_d_w[2 * k + 1], ad);
        cc  = fmaf(w1, enc_s_b[k], cc);
        cc  = fmaf(w2, enc_d_b[k], cc);
        w30 = fmaf(w3, enc_s_w[2 * k + 0], w30);
        w31 = fmaf(w3, enc_s_w[2 * k + 1], w31);
        w3b = fmaf(w3, enc_s_b[k], w3b);
    }
    float4* k4 = (float4*)ws;
    k4[h] = make_float4(a0, a1, ad, v[h]);
    float* f = ws + 4 * HH;
    f[h]          = cc;
    f[HH + h]     = w30;
    f[2 * HH + h] = w31;
    f[3 * HH + h] = w3b;
}

__global__ __launch_bounds__(NT) void sc_main(
    const float* __restrict__ stat, const float* __restrict__ dyn,
    const float* __restrict__ ws,
    const float* __restrict__ enc_s_w, const float* __restrict__ enc_s_b,
    const float* __restrict__ dense_w, const float* __restrict__ dense_b,
    const float* __restrict__ lin_w, const float* __restrict__ lin_b,
    float* __restrict__ out) {
    const int b    = blockIdx.x;
    const int t    = threadIdx.x;
    const int wave = t >> 6;
    const int lane = t & 63;

    __shared__ float cg[HH];
    __shared__ float red[3][NW];
    __shared__ float bc[3];
    __shared__ float hy_sh[HH];

    const float4* k4  = (const float4*)ws;
    const float*  cc  = ws + 4 * HH;
    const float*  w30 = cc + HH;
    const float*  w31 = cc + 2 * HH;
    const float*  w3b = cc + 3 * HH;

    const bool valid = (t < SS);
    float x0 = 0.f, x1 = 0.f, yv = 0.f;
    if (valid) {
        const float* sb = stat + (size_t)b * 2 * SS;
        x0 = sb[t];
        x1 = sb[SS + t];
        yv = dyn[(size_t)b * 2 * SS + SS + t];
    }

    float X0 = 0.f, X1 = 0.f;

    for (int iter = 0; iter < 3; ++iter) {
        if (t < HH) {
            float g = 0.f;
            if (iter > 0) g = fmaf(w30[t], X0, fmaf(w31[t], X1, w3b[t]));
            cg[t] = cc[t] + g;
        }
        __syncthreads();

        float l = -INFINITY;
        if (valid) {
            float acc = 0.f;
            #pragma unroll 8
            for (int h = 0; h < HH; ++h) {
                float4 k = k4[h];
                float z  = fmaf(k.x, x0, fmaf(k.y, x1, fmaf(k.z, yv, cg[h])));
                // tanh(z) = sign(z) * (1-e)/(1+e), e = exp2(-2|z|*log2(e))
                float e2 = __builtin_amdgcn_exp2f(-fabsf(z * 2.8853900817779268f));
                float r  = (1.f - e2) * __builtin_amdgcn_rcpf(1.f + e2);
                acc = fmaf(k.w, copysignf(r, z), acc);
            }
            l = acc;
        }

        // block max
        float wm = l;
        #pragma unroll
        for (int off = 32; off > 0; off >>= 1)
            wm = fmaxf(wm, __shfl_xor(wm, off));
        if (lane == 0) red[0][wave] = wm;
        __syncthreads();
        if (t == 0) {
            float m = red[0][0];
            for (int i = 1; i < NW; ++i) m = fmaxf(m, red[0][i]);
            bc[0] = m;
        }
        __syncthreads();
        const float m = bc[0];

        // softmax-weighted sums: S, S*x0, S*x1 (prob never materialized)
        float p = 0.f;
        if (valid) p = __builtin_amdgcn_exp2f((l - m) * 1.4426950408889634f);
        float s0 = p, s1 = p * x0, s2 = p * x1;
        #pragma unroll
        for (int off = 32; off > 0; off >>= 1) {
            s0 += __shfl_xor(s0, off);
            s1 += __shfl_xor(s1, off);
            s2 += __shfl_xor(s2, off);
        }
        if (lane == 0) { red[0][wave] = s0; red[1][wave] = s1; red[2][wave] = s2; }
        __syncthreads();
        if (t == 0) {
            float d0 = 0.f, d1 = 0.f, d2 = 0.f;
            for (int i = 0; i < NW; ++i) { d0 += red[0][i]; d1 += red[1][i]; d2 += red[2][i]; }
            float inv = 1.0f / d0;  // accurate division
            bc[1] = d1 * inv;
            bc[2] = d2 * inv;
        }
        __syncthreads();
        X0 = bc[1];
        X1 = bc[2];
        __syncthreads();  // protect bc/red before next iteration rewrites
    }

    // hy[h] = esw0[h]*X0 + esw1[h]*X1 + esb[h]  (sum(prob)=1 absorbs the bias)
    if (t < HH)
        hy_sh[t] = fmaf(enc_s_w[2 * t], X0, fmaf(enc_s_w[2 * t + 1], X1, enc_s_b[t]));
    __syncthreads();

    // out[b] = lin_w @ relu(dense_w @ hy + dense_b) + lin_b
    float o = 0.f;
    if (t < HH) {
        const float* dw = dense_w + t * HH;
        float r = dense_b[t];
        #pragma unroll 8
        for (int h = 0; h < HH; ++h) r = fmaf(dw[h], hy_sh[h], r);
        r = fmaxf(r, 0.f);
        o = lin_w[t] * r;
    }
    #pragma unroll
    for (int off = 32; off > 0; off >>= 1) o += __shfl_xor(o, off);
    if (lane == 0) red[0][wave] = o;
    __syncthreads();
    if (t == 0) {
        float s = 0.f;
        for (int i = 0; i < NW; ++i) s += red[0][i];
        out[b] = s + lin_b[0];
    }
}

extern "C" void kernel_launch(void* const* d_in, const int* in_sizes, int n_in,
                              void* d_out, int out_size, void* d_ws, size_t ws_size,
                              hipStream_t stream) {
    const float* stat    = (const float*)d_in[0];
    const float* dyn     = (const float*)d_in[1];
    const float* enc_s_w = (const float*)d_in[2];
    const float* enc_s_b = (const float*)d_in[3];
    const float* enc_d_w = (const float*)d_in[4];
    const float* enc_d_b = (const float*)d_in[5];
    const float* v       = (const float*)d_in[6];
    const float* W       = (const float*)d_in[7];
    const float* dense_w = (const float*)d_in[8];
    const float* dense_b = (const float*)d_in[9];
    const float* lin_w   = (const float*)d_in[10];
    const float* lin_b   = (const float*)d_in[11];
    float* out = (float*)d_out;
    float* ws  = (float*)d_ws;

    const int B = in_sizes[0] / (2 * SS);

    hipLaunchKernelGGL(sc_precompute, dim3(1), dim3(HH), 0, stream,
                       enc_s_w, enc_s_b, enc_d_w, enc_d_b, v, W, ws);
    hipLaunchKernelGGL(sc_main, dim3(B), dim3(NT), 0, stream,
                       stat, dyn, ws, enc_s_w, enc_s_b, dense_w, dense_b,
                       lin_w, lin_b, out);
}

// Round 2
// 46.523 us; speedup vs baseline: 1.2616x; 1.2616x over previous
//
#include <hip/hip_runtime.h>
#include <math.h>

#define HH 128   // hidden size
#define SS 1000  // sequence length
#define NT 1024  // threads per block (16 waves)
#define NW (NT / 64)

#define C1 2.8853900817779268f  // 2*log2(e)
#define C2 1.4426950408889634f  // log2(e)

// ws layout (floats):
//   [0..128)    a0*C1      (W1 @ enc_s_w[:,0], scaled)
//   [128..256)  a1*C1
//   [256..384)  ad*C1      (W2 @ (enc_d_w col sum), scaled)
//   [384..512)  v          (unscaled)
//   [512..640)  cc*C1      (bias part of z, scaled)
//   [640..768)  w30*C1     (W3 @ enc_s_w[:,0], scaled)
//   [768..896)  w31*C1
//   [896..1024) w3b*C1     (W3 @ enc_s_b, scaled)
//   [1024]      sumv*C2
__global__ void sc_precompute(const float* __restrict__ enc_s_w,
                              const float* __restrict__ enc_s_b,
                              const float* __restrict__ enc_d_w,
                              const float* __restrict__ enc_d_b,
                              const float* __restrict__ v,
                              const float* __restrict__ W,
                              float* __restrict__ ws) {
    int h = threadIdx.x;
    if (h < HH) {
        const float* Wr = W + h * (3 * HH);
        float a0 = 0.f, a1 = 0.f, ad = 0.f, cc = 0.f, w30 = 0.f, w31 = 0.f, w3b = 0.f;
        for (int k = 0; k < HH; ++k) {
            float w1 = Wr[k], w2 = Wr[HH + k], w3 = Wr[2 * HH + k];
            a0  = fmaf(w1, enc_s_w[2 * k + 0], a0);
            a1  = fmaf(w1, enc_s_w[2 * k + 1], a1);
            ad  = fmaf(w2, enc_d_w[2 * k + 0] + enc_d_w[2 * k + 1], ad);
            cc  = fmaf(w1, enc_s_b[k], cc);
            cc  = fmaf(w2, enc_d_b[k], cc);
            w30 = fmaf(w3, enc_s_w[2 * k + 0], w30);
            w31 = fmaf(w3, enc_s_w[2 * k + 1], w31);
            w3b = fmaf(w3, enc_s_b[k], w3b);
        }
        ws[h]           = a0 * C1;
        ws[HH + h]      = a1 * C1;
        ws[2 * HH + h]  = ad * C1;
        ws[3 * HH + h]  = v[h];
        ws[4 * HH + h]  = cc * C1;
        ws[5 * HH + h]  = w30 * C1;
        ws[6 * HH + h]  = w31 * C1;
        ws[7 * HH + h]  = w3b * C1;
    }
    __syncthreads();
    if (h == 0) {
        float s = 0.f;
        for (int k = 0; k < HH; ++k) s += v[k];
        ws[8 * HH] = s * C2;
    }
}

__global__ __launch_bounds__(NT) void sc_main(
    const float* __restrict__ stat, const float* __restrict__ dyn,
    const float* __restrict__ ws,
    const float* __restrict__ enc_s_w, const float* __restrict__ enc_s_b,
    const float* __restrict__ dense_w, const float* __restrict__ dense_b,
    const float* __restrict__ lin_w, const float* __restrict__ lin_b,
    float* __restrict__ out) {
    const int b    = blockIdx.x;
    const int t    = threadIdx.x;
    const int wave = t >> 6;
    const int lane = t & 63;

    __shared__ __align__(16) float kc[4 * HH];   // a0,a1,ad,v (scaled where needed)
    __shared__ __align__(16) float cgs[HH];      // per-iter bias (scaled)
    __shared__ float4 red4[NW];
    __shared__ float hy_sh[HH];

    // stage iteration-invariant constants into LDS
    if (t < 4 * HH) kc[t] = ws[t];

    const float* ccs = ws + 4 * HH;
    const float* w30 = ws + 5 * HH;
    const float* w31 = ws + 6 * HH;
    const float* w3b = ws + 7 * HH;
    const float  svc2 = ws[8 * HH];

    const bool valid = (t < SS);
    float x0 = 0.f, x1 = 0.f, yv = 0.f;
    if (valid) {
        const float* sb = stat + (size_t)b * 2 * SS;
        x0 = sb[t];
        x1 = sb[SS + t];
        yv = dyn[(size_t)b * 2 * SS + SS + t];
    }

    float X0 = 0.f, X1 = 0.f;

    for (int iter = 0; iter < 3; ++iter) {
        if (t < HH) {
            float g = ccs[t];
            if (iter > 0) g += fmaf(w30[t], X0, fmaf(w31[t], X1, w3b[t]));
            cgs[t] = g;
        }
        __syncthreads();  // A: cgs (and kc on iter 0) visible

        // acc = sum_h v[h] * rcp(1 + exp2(z_scaled[h]));  logit = sumv - 2*acc
        float acc = 0.f;
        const float4* A0 = (const float4*)kc;
        const float4* A1 = (const float4*)(kc + HH);
        const float4* AD = (const float4*)(kc + 2 * HH);
        const float4* VV = (const float4*)(kc + 3 * HH);
        const float4* CG = (const float4*)cgs;
        #pragma unroll 4
        for (int j = 0; j < HH / 4; ++j) {
            float4 a0 = A0[j], a1 = A1[j], ad = AD[j], vv = VV[j], cg = CG[j];
            float z0 = fmaf(a0.x, x0, fmaf(a1.x, x1, fmaf(ad.x, yv, cg.x)));
            float z1 = fmaf(a0.y, x0, fmaf(a1.y, x1, fmaf(ad.y, yv, cg.y)));
            float z2 = fmaf(a0.z, x0, fmaf(a1.z, x1, fmaf(ad.z, yv, cg.z)));
            float z3 = fmaf(a0.w, x0, fmaf(a1.w, x1, fmaf(ad.w, yv, cg.w)));
            float e0 = __builtin_amdgcn_exp2f(z0);
            float e1 = __builtin_amdgcn_exp2f(z1);
            float e2 = __builtin_amdgcn_exp2f(z2);
            float e3 = __builtin_amdgcn_exp2f(z3);
            float r0 = __builtin_amdgcn_rcpf(1.f + e0);
            float r1 = __builtin_amdgcn_rcpf(1.f + e1);
            float r2 = __builtin_amdgcn_rcpf(1.f + e2);
            float r3 = __builtin_amdgcn_rcpf(1.f + e3);
            acc = fmaf(vv.x, r0, acc);
            acc = fmaf(vv.y, r1, acc);
            acc = fmaf(vv.z, r2, acc);
            acc = fmaf(vv.w, r3, acc);
        }

        // unnormalized softmax weight (no max-sub: |logit| <= sum|v| ~ 14, safe)
        float p = valid ? __builtin_amdgcn_exp2f(fmaf(-C1, acc, svc2)) : 0.f;

        float s0 = p, s1 = p * x0, s2 = p * x1;
        #pragma unroll
        for (int off = 32; off > 0; off >>= 1) {
            s0 += __shfl_xor(s0, off);
            s1 += __shfl_xor(s1, off);
            s2 += __shfl_xor(s2, off);
        }
        if (lane == 0) red4[wave] = make_float4(s0, s1, s2, 0.f);
        __syncthreads();  // B: red4 visible

        // all-lane cross-wave reduce: every lane reads one of the 16 partials
        float4 w4 = red4[lane & 15];
        #pragma unroll
        for (int off = 1; off < 16; off <<= 1) {
            w4.x += __shfl_xor(w4.x, off);
            w4.y += __shfl_xor(w4.y, off);
            w4.z += __shfl_xor(w4.z, off);
        }
        float inv = __builtin_amdgcn_rcpf(w4.x);
        X0 = w4.y * inv;
        X1 = w4.z * inv;
    }

    // hy[h] = enc_s_w[h,0]*X0 + enc_s_w[h,1]*X1 + enc_s_b[h]
    if (t < HH)
        hy_sh[t] = fmaf(enc_s_w[2 * t], X0, fmaf(enc_s_w[2 * t + 1], X1, enc_s_b[t]));
    __syncthreads();

    // out[b] = lin_w @ relu(dense_w @ hy + dense_b) + lin_b
    float o = 0.f;
    if (t < HH) {
        const float* dw = dense_w + t * HH;
        float r = dense_b[t];
        #pragma unroll 8
        for (int h = 0; h < HH; ++h) r = fmaf(dw[h], hy_sh[h], r);
        o = lin_w[t] * fmaxf(r, 0.f);
    }
    #pragma unroll
    for (int off = 32; off > 0; off >>= 1) o += __shfl_xor(o, off);
    if (lane == 0) red4[wave].x = o;
    __syncthreads();
    if (t == 0) {
        float s = 0.f;
        for (int i = 0; i < NW; ++i) s += red4[i].x;
        out[b] = s + lin_b[0];
    }
}

extern "C" void kernel_launch(void* const* d_in, const int* in_sizes, int n_in,
                              void* d_out, int out_size, void* d_ws, size_t ws_size,
                              hipStream_t stream) {
    const float* stat    = (const float*)d_in[0];
    const float* dyn     = (const float*)d_in[1];
    const float* enc_s_w = (const float*)d_in[2];
    const float* enc_s_b = (const float*)d_in[3];
    const float* enc_d_w = (const float*)d_in[4];
    const float* enc_d_b = (const float*)d_in[5];
    const float* v       = (const float*)d_in[6];
    const float* W       = (const float*)d_in[7];
    const float* dense_w = (const float*)d_in[8];
    const float* dense_b = (const float*)d_in[9];
    const float* lin_w   = (const float*)d_in[10];
    const float* lin_b   = (const float*)d_in[11];
    float* out = (float*)d_out;
    float* ws  = (float*)d_ws;

    const int B = in_sizes[0] / (2 * SS);

    hipLaunchKernelGGL(sc_precompute, dim3(1), dim3(HH), 0, stream,
                       enc_s_w, enc_s_b, enc_d_w, enc_d_b, v, W, ws);
    hipLaunchKernelGGL(sc_main, dim3(B), dim3(NT), 0, stream,
                       stat, dyn, ws, enc_s_w, enc_s_b, dense_w, dense_b,
                       lin_w, lin_b, out);
}